// Round 1
// baseline (387.391 us; speedup 1.0000x reference)
//
#include <hip/hip_runtime.h>
#include <stdint.h>
#include <stddef.h>

// EdgeLearning: out[e] = W2 @ leaky(W1 @ [x[ei0[e]], x[ei1[e]], ea[e]] + b1) + b2
// bf16 MFMA (16x16x32), fp32 accumulate. Layouts per verified gfx950 mappings:
//   A frag: A[m=lane&15][k=quad*8+j]   B frag: B[n=lane&15][k=quad*8+j]
//   C/D:    col=lane&15, row=quad*4+reg
// Per wave: 32 edges (2 M-tiles). W1 bf16 in LDS (row pad 160->168 keeps 16B
// alignment and gives conflict-free 2-way bank pattern: stride 336B -> 84 dw
// -> lane n hits bank 20n%32). W2 frags live in registers (16 x short8 = 64
// VGPR, tile-invariant). h goes C-layout -> A-layout through a 32x40 per-wave
// LDS chunk (stride 80B -> 20 dw -> 2-way free), streamed per 32-col chunk so
// total LDS = 43008 + 4*2560 = 53248 B < 64KB.

typedef short short8 __attribute__((ext_vector_type(8)));
typedef float f32x4 __attribute__((ext_vector_type(4)));

__device__ __forceinline__ short f2bf(float f) {
  union { float f; unsigned u; } v; v.f = f;
  unsigned r = (v.u + 0x7fffu + ((v.u >> 16) & 1u)) >> 16;  // RNE
  return (short)r;
}

__device__ __forceinline__ short8 cvt8(const float* __restrict__ p) {
  f32x4 a = *(const f32x4*)p;
  f32x4 b = *(const f32x4*)(p + 4);
  short8 r;
  r[0] = f2bf(a[0]); r[1] = f2bf(a[1]); r[2] = f2bf(a[2]); r[3] = f2bf(a[3]);
  r[4] = f2bf(b[0]); r[5] = f2bf(b[1]); r[6] = f2bf(b[2]); r[7] = f2bf(b[3]);
  return r;
}

__global__ __launch_bounds__(256, 2)
void edge_mlp(const float* __restrict__ x, const int* __restrict__ ei,
              const float* __restrict__ ea, const float* __restrict__ W1,
              const float* __restrict__ b1, const float* __restrict__ W2,
              const float* __restrict__ b2, float* __restrict__ out,
              int E, int ntiles)
{
  __shared__ short sW1[128 * 168];   // bf16 bits, padded rows
  __shared__ short sH[4][32 * 40];   // per-wave h chunk (32 edges x 32 cols, pad to 40)

  const int tid  = threadIdx.x;
  const int lane = tid & 63;
  const int wave = tid >> 6;
  const int m    = lane & 15;
  const int quad = lane >> 4;

  // Stage W1 -> LDS as bf16 (once per block; amortized over grid-stride tiles)
  for (int i = tid; i < 128 * 160; i += 256) {
    int n = i / 160;
    int k = i - n * 160;
    sW1[n * 168 + k] = f2bf(W1[i]);
  }

  // W2 fragments in registers: B2[k][o], o = ot*16+m, k = c*32 + quad*8 + j
  short8 w2f[4][4];
#pragma unroll
  for (int ot = 0; ot < 4; ++ot)
#pragma unroll
    for (int c = 0; c < 4; ++c)
      w2f[ot][c] = cvt8(W2 + (size_t)(ot * 16 + m) * 128 + c * 32 + quad * 8);

  float b1v[8], b2v[4];
#pragma unroll
  for (int nt = 0; nt < 8; ++nt) b1v[nt] = b1[nt * 16 + m];
#pragma unroll
  for (int ot = 0; ot < 4; ++ot) b2v[ot] = b2[ot * 16 + m];

  __syncthreads();

  short* sHw = sH[wave];

  for (int t = blockIdx.x; t < ntiles; t += gridDim.x) {
    const int ebase = t * 128 + wave * 32;

    // Gather A fragments for layer 1: mask = [x_i | x_j | ea], K = 160 (5 kt)
    short8 a1[2][5];
#pragma unroll
    for (int mt = 0; mt < 2; ++mt) {
      int e = ebase + mt * 16 + m;
      e = (e < E) ? e : (E - 1);
      const int i0 = ei[e];
      const int i1 = ei[E + e];
      const float* r0 = x + (size_t)i0 * 64 + quad * 8;
      const float* r1 = x + (size_t)i1 * 64 + quad * 8;
      a1[mt][0] = cvt8(r0);
      a1[mt][1] = cvt8(r0 + 32);
      a1[mt][2] = cvt8(r1);
      a1[mt][3] = cvt8(r1 + 32);
      a1[mt][4] = cvt8(ea + (size_t)e * 32 + quad * 8);
    }

    f32x4 acc2[2][4];
#pragma unroll
    for (int mt = 0; mt < 2; ++mt)
#pragma unroll
      for (int ot = 0; ot < 4; ++ot) {
        f32x4 z = { b2v[ot], b2v[ot], b2v[ot], b2v[ot] };
        acc2[mt][ot] = z;
      }

    // Stream h in 32-col chunks: produce 2 n-tiles, round-trip LDS, consume in layer 2
#pragma unroll
    for (int c = 0; c < 4; ++c) {
#pragma unroll
      for (int sub = 0; sub < 2; ++sub) {
        const int nt = c * 2 + sub;
        f32x4 h0 = { b1v[nt], b1v[nt], b1v[nt], b1v[nt] };
        f32x4 h1 = h0;
#pragma unroll
        for (int kt = 0; kt < 5; ++kt) {
          short8 bf = *(const short8*)&sW1[(nt * 16 + m) * 168 + kt * 32 + quad * 8];
          h0 = __builtin_amdgcn_mfma_f32_16x16x32_bf16(a1[0][kt], bf, h0, 0, 0, 0);
          h1 = __builtin_amdgcn_mfma_f32_16x16x32_bf16(a1[1][kt], bf, h1, 0, 0, 0);
        }
#pragma unroll
        for (int r = 0; r < 4; ++r) {
          float v0 = h0[r]; v0 = (v0 >= 0.0f) ? v0 : 0.01f * v0;
          float v1 = h1[r]; v1 = (v1 >= 0.0f) ? v1 : 0.01f * v1;
          sHw[(quad * 4 + r) * 40 + sub * 16 + m]      = f2bf(v0);  // m-tile 0: rows 0..15
          sHw[(16 + quad * 4 + r) * 40 + sub * 16 + m] = f2bf(v1);  // m-tile 1: rows 16..31
        }
      }
#pragma unroll
      for (int mt = 0; mt < 2; ++mt) {
        short8 a2 = *(const short8*)&sHw[(mt * 16 + m) * 40 + quad * 8];
#pragma unroll
        for (int ot = 0; ot < 4; ++ot)
          acc2[mt][ot] = __builtin_amdgcn_mfma_f32_16x16x32_bf16(a2, w2f[ot][c], acc2[mt][ot], 0, 0, 0);
      }
    }

    // Store: out[e][o], e = ebase + mt*16 + quad*4 + r, o = ot*16 + m
#pragma unroll
    for (int mt = 0; mt < 2; ++mt)
#pragma unroll
      for (int ot = 0; ot < 4; ++ot)
#pragma unroll
        for (int r = 0; r < 4; ++r) {
          int er = ebase + mt * 16 + quad * 4 + r;
          if (er < E) out[(size_t)er * 64 + ot * 16 + m] = acc2[mt][ot][r];
        }
  }
}

extern "C" void kernel_launch(void* const* d_in, const int* in_sizes, int n_in,
                              void* d_out, int out_size, void* d_ws, size_t ws_size,
                              hipStream_t stream) {
  const float* x  = (const float*)d_in[0];
  const int*   ei = (const int*)d_in[1];
  const float* ea = (const float*)d_in[2];
  const float* W1 = (const float*)d_in[3];
  const float* b1 = (const float*)d_in[4];
  const float* W2 = (const float*)d_in[5];
  const float* b2 = (const float*)d_in[6];
  float* out = (float*)d_out;

  const int E = in_sizes[1] / 2;           // edge_index is [2, E]
  const int ntiles = (E + 127) / 128;      // 128 edges per block (32 per wave)
  int grid = ntiles < 1250 ? ntiles : 1250; // persistent-ish: amortize W staging

  edge_mlp<<<grid, 256, 0, stream>>>(x, ei, ea, W1, b1, W2, b2, out, E, ntiles);
}